// Round 1
// baseline (69.139 us; speedup 1.0000x reference)
//
#include <hip/hip_runtime.h>

// ForceThresholdCost: reference collapses to
//   w[k]  = 1000 * sum_c (sum_i normals[c,i]) * (sum_j jac[c,j,k])   (k<7)
//   bias  = sum_c forces[c] - sum_k w[k]*start[k]
//   fi    = bias + sum_k w[k]*state[n,h,k]
//   out   = fi > 3 ? 10000 : 0
// Single fused kernel: every block recomputes w/bias from the tiny inputs
// (normals 64x3, jac 64x3x7, forces 64 — ~6.5KB, L2-resident), then does the
// elementwise pass. fp64 used for w/bias/dot to avoid boundary flips at the
// fi>3 threshold (output is discontinuous; a flip costs 10000 absmax).

#define FTC_C 64
#define FTC_D 7

__global__ __launch_bounds__(256) void ForceThresholdCost_kernel(
    const float* __restrict__ start_state,   // [7]
    const float* __restrict__ state_batch,   // [NTOT*7]
    const float* __restrict__ normals,       // [64*3]
    const float* __restrict__ jac,           // [64*3*7]
    const float* __restrict__ forces,        // [64]
    float* __restrict__ out,                 // [NTOT]
    int ntot)
{
    __shared__ double wpart[FTC_C][FTC_D];
    __shared__ double wred[FTC_D];
    __shared__ double fsum_s;
    __shared__ double bias_s;

    const int tid = threadIdx.x;

    // --- per-c contributions (threads 0..63) ---
    if (tid < FTC_C) {
        double sn = (double)normals[tid * 3 + 0]
                  + (double)normals[tid * 3 + 1]
                  + (double)normals[tid * 3 + 2];
        #pragma unroll
        for (int k = 0; k < FTC_D; ++k) {
            double tk = (double)jac[tid * 21 + 0 * 7 + k]
                      + (double)jac[tid * 21 + 1 * 7 + k]
                      + (double)jac[tid * 21 + 2 * 7 + k];
            wpart[tid][k] = 1000.0 * sn * tk;
        }
    }
    __syncthreads();

    // --- reduce over c (threads 0..6 handle one k each; thread 7 sums forces) ---
    if (tid < FTC_D) {
        double s = 0.0;
        for (int c = 0; c < FTC_C; ++c) s += wpart[c][tid];
        wred[tid] = s;
    } else if (tid == FTC_D) {
        double f = 0.0;
        for (int c = 0; c < FTC_C; ++c) f += (double)forces[c];
        fsum_s = f;
    }
    __syncthreads();

    if (tid == 0) {
        double b = fsum_s;
        #pragma unroll
        for (int k = 0; k < FTC_D; ++k) b -= wred[k] * (double)start_state[k];
        bias_s = b;
    }
    __syncthreads();

    // --- elementwise pass ---
    double w0 = wred[0], w1 = wred[1], w2 = wred[2], w3 = wred[3];
    double w4 = wred[4], w5 = wred[5], w6 = wred[6];
    double bias = bias_s;

    int idx = blockIdx.x * 256 + tid;
    if (idx < ntot) {
        const float* sp = state_batch + (size_t)idx * FTC_D;
        double fi = bias;
        fi = fma((double)sp[0], w0, fi);
        fi = fma((double)sp[1], w1, fi);
        fi = fma((double)sp[2], w2, fi);
        fi = fma((double)sp[3], w3, fi);
        fi = fma((double)sp[4], w4, fi);
        fi = fma((double)sp[5], w5, fi);
        fi = fma((double)sp[6], w6, fi);
        out[idx] = (fi > 3.0) ? 10000.0f : 0.0f;
    }
}

extern "C" void kernel_launch(void* const* d_in, const int* in_sizes, int n_in,
                              void* d_out, int out_size, void* d_ws, size_t ws_size,
                              hipStream_t stream) {
    const float* start_state = (const float*)d_in[0];  // (1,7)
    const float* state_batch = (const float*)d_in[1];  // (N,H,7)
    const float* normals     = (const float*)d_in[2];  // (64,3)
    const float* jac         = (const float*)d_in[3];  // (64,3,7)
    const float* forces      = (const float*)d_in[4];  // (64,)
    float* out = (float*)d_out;

    int ntot = in_sizes[1] / FTC_D;          // N*H = 262144
    int grid = (ntot + 255) / 256;           // 1024 blocks

    ForceThresholdCost_kernel<<<grid, 256, 0, stream>>>(
        start_state, state_batch, normals, jac, forces, out, ntot);
}

// Round 2
// 67.726 us; speedup vs baseline: 1.0209x; 1.0209x over previous
//
#include <hip/hip_runtime.h>

// ForceThresholdCost, round 2.
// Algebra (k_c is all-1000):
//   w[k]  = 1000 * sum_c (sum_i normals[c,i]) * (sum_j jac[c,j,k])   (k<7)
//   bias  = sum_c forces[c] - sum_k w[k]*start[k]
//   out[n] = (bias + sum_k w[k]*state[n,k]) > 3 ? 10000 : 0
//
// Kernel 1: one wave, shuffle-butterfly reduction over c=0..63 -> d_ws double[8].
// Kernel 2: 4 rows/thread, 7x float4 loads + 1x float4 store, fp64 dot
//           (boundary-flip safety at the fi>3 discontinuity).

#define FTC_D 7

__global__ __launch_bounds__(64) void ftc_setup_kernel(
    const float* __restrict__ start_state,   // [7]
    const float* __restrict__ normals,       // [64*3]
    const float* __restrict__ jac,           // [64*3*7]
    const float* __restrict__ forces,        // [64]
    double* __restrict__ wb)                 // [8] out: w[0..6], bias
{
    const int c = threadIdx.x;               // 0..63, one lane per contact
    double sn = (double)normals[c * 3 + 0]
              + (double)normals[c * 3 + 1]
              + (double)normals[c * 3 + 2];
    double vals[8];
    #pragma unroll
    for (int k = 0; k < FTC_D; ++k) {
        double tk = (double)jac[c * 21 + 0 * 7 + k]
                  + (double)jac[c * 21 + 1 * 7 + k]
                  + (double)jac[c * 21 + 2 * 7 + k];
        vals[k] = 1000.0 * sn * tk;
    }
    vals[7] = (double)forces[c];

    // 64-lane butterfly reduction, 6 steps, 8 doubles per lane
    #pragma unroll
    for (int off = 32; off > 0; off >>= 1) {
        #pragma unroll
        for (int k = 0; k < 8; ++k)
            vals[k] += __shfl_xor(vals[k], off, 64);
    }

    if (c == 0) {
        double b = vals[7];
        #pragma unroll
        for (int k = 0; k < FTC_D; ++k) b -= vals[k] * (double)start_state[k];
        #pragma unroll
        for (int k = 0; k < FTC_D; ++k) wb[k] = vals[k];
        wb[7] = b;
    }
}

__global__ __launch_bounds__(256) void ftc_main_kernel(
    const float* __restrict__ state_batch,   // [ntot*7]
    const double* __restrict__ wb,           // [8]: w[0..6], bias
    float* __restrict__ out,                 // [ntot]
    int nquad)                               // ntot/4
{
    // Uniform (wave-invariant) loads -> scalar regs
    double w0 = wb[0], w1 = wb[1], w2 = wb[2], w3 = wb[3];
    double w4 = wb[4], w5 = wb[5], w6 = wb[6];
    double bias = wb[7];

    int t = blockIdx.x * 256 + threadIdx.x;
    if (t < nquad) {
        // 4 rows = 28 contiguous floats, 112B-aligned per thread
        const float4* p = (const float4*)(state_batch + (size_t)t * 28);
        float v[28];
        float4* vv = (float4*)v;
        #pragma unroll
        for (int j = 0; j < 7; ++j) vv[j] = p[j];

        float4 o;
        float* ov = &o.x;
        #pragma unroll
        for (int r = 0; r < 4; ++r) {
            const float* s = v + r * 7;
            double fi = bias;
            fi = fma((double)s[0], w0, fi);
            fi = fma((double)s[1], w1, fi);
            fi = fma((double)s[2], w2, fi);
            fi = fma((double)s[3], w3, fi);
            fi = fma((double)s[4], w4, fi);
            fi = fma((double)s[5], w5, fi);
            fi = fma((double)s[6], w6, fi);
            ov[r] = (fi > 3.0) ? 10000.0f : 0.0f;
        }
        ((float4*)out)[t] = o;
    }
}

extern "C" void kernel_launch(void* const* d_in, const int* in_sizes, int n_in,
                              void* d_out, int out_size, void* d_ws, size_t ws_size,
                              hipStream_t stream) {
    const float* start_state = (const float*)d_in[0];  // (1,7)
    const float* state_batch = (const float*)d_in[1];  // (N,H,7)
    const float* normals     = (const float*)d_in[2];  // (64,3)
    const float* jac         = (const float*)d_in[3];  // (64,3,7)
    const float* forces      = (const float*)d_in[4];  // (64,)
    float* out = (float*)d_out;
    double* wb = (double*)d_ws;                        // 64 bytes of scratch

    int ntot  = in_sizes[1] / FTC_D;                   // N*H = 262144
    int nquad = ntot / 4;                              // 65536 (ntot % 4 == 0)
    int grid  = (nquad + 255) / 256;                   // 256 blocks -> 1/CU

    ftc_setup_kernel<<<1, 64, 0, stream>>>(start_state, normals, jac, forces, wb);
    ftc_main_kernel<<<grid, 256, 0, stream>>>(state_batch, wb, out, nquad);
}